// Round 5
// baseline (421.492 us; speedup 1.0000x reference)
//
#include <hip/hip_runtime.h>
#include <math.h>

// LinearAttention — all GEMMs bf16 MFMA 16x16x32, fragment loads direct from
// global where layout permits (coalesced 64B lines via 4 quads x 16B).
//
// R1: k1 split into q-pass (32 AGPR) then kv-pass (64 AGPR), (256,4).
// R2: part f32 -> bf16 (halves the part round-trip).  k1 = 109 us champion.
// R3: FAILED (reg-prefetch spilled at 128-reg cap).
// R4: FAILED ((256,3) didn't give payload residency, cost occupancy).
// R5: k1 reverted to exact R2. k3 rewritten for 128-px tiles (1024 blocks):
//     2x work per phase transition, fuller store lines, AGPR peak 32 via
//     attn nt-halves + Wout 16-row quarters. k4 folded into k5; k5 8192 blocks.
//
// ws layout (float units):
//   q_wsT   @ 0         : bf16[32*4096*128]  [b][px][ch] softmaxed*SCALE q   (8388608 f)
//   wqkv_bf @ 8388608   : bf16[384*256]      row-major                      (49152 f)
//   wout_bf @ 8437760   : bf16[256*128]      row-major                      (16384 f)
//   ctxT_bf @ 8454144   : bf16[32*4*32*32]   [b][h][e][d] (transposed)      (65536 f)
//   part    @ 16777216  : bf16[2048][4096]   per-block context partials     (4194304 f)
//   gstats  @ 25165824  : f32 [128]

#define NPIX 4096
#define SCALE 0.17677669529663687f

typedef __bf16 bf16;
typedef __bf16 bf16x4 __attribute__((ext_vector_type(4)));
typedef __bf16 bf16x8 __attribute__((ext_vector_type(8)));
typedef float  f32x4  __attribute__((ext_vector_type(4)));

// ---------------------------------------------------------------------------
__global__ __launch_bounds__(256) void k0_convert(
    const float* __restrict__ Wqkv, const float* __restrict__ Wout,
    bf16* __restrict__ wqkv_bf, bf16* __restrict__ wout_bf)
{
    int i = blockIdx.x * 256 + threadIdx.x;   // < 131072
    if (i < 98304) wqkv_bf[i] = (bf16)Wqkv[i];
    else           wout_bf[i - 98304] = (bf16)Wout[i - 98304];
}

// ---------------------------------------------------------------------------
// k1: block = (batch b, 64-px tile). 4 waves, wave s = head s.  (exact R2)
// qkv[384,64] = Wqkv x x. A-frags direct from global bf16 Wqkv (L2-hot).
// B-frags from LDS xT (transposed, XOR-swizzled). Barrier-free K-loop.
// Two passes over xT: pass1 = q rows (softmax+store), pass2 = k,v rows.
// LDS: xT 16384 bf16 (32 KB); overlay phase2: k/v [4][32][72]*2 = 36864 B.
// ---------------------------------------------------------------------------
__global__ __launch_bounds__(256, 4) void k1_qkv(
    const float* __restrict__ x, const bf16* __restrict__ wqkv_bf,
    const float* __restrict__ bqkv, bf16* __restrict__ q_wsT,
    bf16* __restrict__ part)
{
    __shared__ __align__(16) bf16 sm[18432];   // 36864 B
    bf16* xT = sm;   // 16384 bf16 [px][256ch], group(8) swizzle gp = g ^ (px&7)

    const int blk  = blockIdx.x;
    const int b    = blk >> 6;
    const int n0   = (blk & 63) << 6;
    const int tid  = threadIdx.x;
    const int lane = tid & 63;
    const int s    = __builtin_amdgcn_readfirstlane(tid >> 6);
    const int m16  = lane & 15;
    const int quad = lane >> 4;

    // stage xT (transposed, bf16, swizzled)
    const float* xb = x + (size_t)b * (256 * NPIX) + n0;
    {
        const int px  = tid & 63;
        const int cq0 = tid >> 6;
        float vv[16][4];
        #pragma unroll
        for (int it = 0; it < 16; ++it) {
            const float* xp = xb + (size_t)(cq0 + 4*it) * 4 * NPIX + px;
            vv[it][0] = xp[0];
            vv[it][1] = xp[NPIX];
            vv[it][2] = xp[2*NPIX];
            vv[it][3] = xp[3*NPIX];
        }
        #pragma unroll
        for (int it = 0; it < 16; ++it) {
            int cq = cq0 + 4*it;
            int gp = (cq >> 1) ^ (px & 7);
            bf16x4 pk = { (bf16)vv[it][0], (bf16)vv[it][1],
                          (bf16)vv[it][2], (bf16)vv[it][3] };
            *(bf16x4*)&xT[px*256 + gp*8 + (cq & 1)*4] = pk;
        }
    }
    __syncthreads();

    // ---- pass 1: q GEMM (rows s*32 .. s*32+31), softmax over d, store q_wsT
    {
        f32x4 qacc[2][4] = {};
        for (int kc = 0; kc < 8; ++kc) {
            bf16x8 bfr[4];
            #pragma unroll
            for (int nt = 0; nt < 4; ++nt) {
                int px = nt*16 + m16;
                int gp = (kc*4 + quad) ^ (px & 7);
                bfr[nt] = *(const bf16x8*)&xT[px*256 + gp*8];
            }
            #pragma unroll
            for (int mt = 0; mt < 2; ++mt) {
                int row = s*32 + mt*16 + m16;
                bf16x8 afr = *(const bf16x8*)&wqkv_bf[(size_t)row*256 + kc*32 + quad*8];
                #pragma unroll
                for (int nt = 0; nt < 4; ++nt)
                    qacc[mt][nt] = __builtin_amdgcn_mfma_f32_16x16x32_bf16(afr, bfr[nt], qacc[mt][nt], 0, 0, 0);
            }
        }
        float bq[8];
        #pragma unroll
        for (int j = 0; j < 8; ++j)
            bq[j] = bqkv[s*32 + (j >> 2)*16 + quad*4 + (j & 3)];

        #pragma unroll
        for (int nt = 0; nt < 4; ++nt) {
            float v[8]; float mx = -1e30f;
            #pragma unroll
            for (int j = 0; j < 8; ++j) { v[j] = qacc[j>>2][nt][j&3] + bq[j]; mx = fmaxf(mx, v[j]); }
            mx = fmaxf(mx, __shfl_xor(mx, 16));
            mx = fmaxf(mx, __shfl_xor(mx, 32));
            float sum = 0.f;
            #pragma unroll
            for (int j = 0; j < 8; ++j) { v[j] = __expf(v[j] - mx); sum += v[j]; }
            sum += __shfl_xor(sum, 16);
            sum += __shfl_xor(sum, 32);
            float rs = SCALE / sum;
            size_t rowb = (size_t)(b*4096 + n0 + nt*16 + m16) * 128;
            #pragma unroll
            for (int mt = 0; mt < 2; ++mt) {
                bf16x4 pk = { (bf16)(v[mt*4+0]*rs), (bf16)(v[mt*4+1]*rs),
                              (bf16)(v[mt*4+2]*rs), (bf16)(v[mt*4+3]*rs) };
                *(bf16x4*)&q_wsT[rowb + s*32 + mt*16 + quad*4] = pk;
            }
        }
    }

    // ---- pass 2: k,v GEMM (rows 128+s*32.. and 256+s*32..)
    f32x4 acc[4][4] = {};   // m-tiles: k0,k1,v0,v1 ; 4 n-tiles
    for (int kc = 0; kc < 8; ++kc) {
        bf16x8 bfr[4];
        #pragma unroll
        for (int nt = 0; nt < 4; ++nt) {
            int px = nt*16 + m16;
            int gp = (kc*4 + quad) ^ (px & 7);
            bfr[nt] = *(const bf16x8*)&xT[px*256 + gp*8];
        }
        #pragma unroll
        for (int mt = 0; mt < 4; ++mt) {
            int row = 128 + (mt >> 1)*128 + s*32 + (mt & 1)*16 + m16;
            bf16x8 afr = *(const bf16x8*)&wqkv_bf[(size_t)row*256 + kc*32 + quad*8];
            #pragma unroll
            for (int nt = 0; nt < 4; ++nt)
                acc[mt][nt] = __builtin_amdgcn_mfma_f32_16x16x32_bf16(afr, bfr[nt], acc[mt][nt], 0, 0, 0);
        }
    }

    float bk[8], bv[8];
    #pragma unroll
    for (int j = 0; j < 8; ++j) {
        int rr = (j >> 2)*16 + quad*4 + (j & 3);
        bk[j] = bqkv[128 + s*32 + rr];
        bv[j] = bqkv[256 + s*32 + rr];
    }

    // k softmax + v bias -> LDS overlay (xT dead; barrier for WAR)
    __syncthreads();
    bf16* kl = sm + s*2304;          // [32][72]
    bf16* vl = sm + 9216 + s*2304;   // [32][72]
    #pragma unroll
    for (int nt = 0; nt < 4; ++nt) {
        float v[8]; float mx = -1e30f;
        #pragma unroll
        for (int j = 0; j < 8; ++j) { v[j] = acc[j>>2][nt][j&3] + bk[j]; mx = fmaxf(mx, v[j]); }
        mx = fmaxf(mx, __shfl_xor(mx, 16));
        mx = fmaxf(mx, __shfl_xor(mx, 32));
        float sum = 0.f;
        #pragma unroll
        for (int j = 0; j < 8; ++j) { v[j] = __expf(v[j] - mx); sum += v[j]; }
        sum += __shfl_xor(sum, 16);
        sum += __shfl_xor(sum, 32);
        float rs = 1.f / sum;
        #pragma unroll
        for (int j = 0; j < 8; ++j) {
            int d  = (j>>2)*16 + quad*4 + (j&3);
            int px = nt*16 + m16;
            kl[d*72 + px] = (bf16)(v[j] * rs);
            vl[d*72 + px] = (bf16)(acc[2 + (j>>2)][nt][j&3] + bv[j]);
        }
    }
    __syncthreads();

    // context partial: ctx[d][e] = sum_p k[d][p]*v[e][p]
    f32x4 cacc[2][2] = {};
    #pragma unroll
    for (int ks = 0; ks < 2; ++ks) {
        bf16x8 ak[2], bvv[2];
        #pragma unroll
        for (int mt = 0; mt < 2; ++mt)
            ak[mt] = *(const bf16x8*)&kl[(mt*16 + m16)*72 + ks*32 + quad*8];
        #pragma unroll
        for (int nt = 0; nt < 2; ++nt)
            bvv[nt] = *(const bf16x8*)&vl[(nt*16 + m16)*72 + ks*32 + quad*8];
        #pragma unroll
        for (int mt = 0; mt < 2; ++mt)
            #pragma unroll
            for (int nt = 0; nt < 2; ++nt)
                cacc[mt][nt] = __builtin_amdgcn_mfma_f32_16x16x32_bf16(ak[mt], bvv[nt], cacc[mt][nt], 0, 0, 0);
    }
    bf16* pdst = part + (size_t)blk * 4096 + s*1024;
    #pragma unroll
    for (int mt = 0; mt < 2; ++mt)
        #pragma unroll
        for (int nt = 0; nt < 2; ++nt)
            #pragma unroll
            for (int r = 0; r < 4; ++r)
                pdst[(mt*16 + quad*4 + r)*32 + nt*16 + m16] = (bf16)cacc[mt][nt][r];
}

// ---------------------------------------------------------------------------
__global__ __launch_bounds__(256) void k2_reduce(
    const bf16* __restrict__ part, bf16* __restrict__ ctxT_bf)
{
    int i = blockIdx.x * 256 + threadIdx.x;   // < 131072
    int b = i >> 12, r = i & 4095;
    const bf16* p = part + (size_t)b * 64 * 4096 + r;
    float sum = 0.f;
    #pragma unroll 8
    for (int j = 0; j < 64; ++j) sum += (float)p[(size_t)j * 4096];
    int h = r >> 10, d = (r >> 5) & 31, e = r & 31;
    ctxT_bf[(size_t)((b*4 + h)*32 + e)*32 + d] = (bf16)sum;   // transposed
}

// ---------------------------------------------------------------------------
// k3: block = (b, 128-px tile), 1024 blocks. Wave s: attn for head s (two
// nt-halves, 32 AGPR each), then out rows s*64..+63 in four 16-row quarters
// (32 AGPR each). LDS: attnT [128][128] bf16 XOR-swizzled (32 KB) + red 2 KB.
// ---------------------------------------------------------------------------
__global__ __launch_bounds__(256, 4) void k3_out(
    const bf16* __restrict__ q_wsT, const bf16* __restrict__ ctxT_bf,
    const bf16* __restrict__ wout_bf, const float* __restrict__ bout,
    float* __restrict__ out, float* __restrict__ gstats)
{
    __shared__ __align__(16) bf16 attnT[16384];   // [128 px][128 ch]
    __shared__ float red[512];
    const int blk  = blockIdx.x;
    const int b    = blk >> 5;
    const int n0   = (blk & 31) << 7;
    const int tid  = threadIdx.x;
    const int lane = tid & 63;
    const int s    = __builtin_amdgcn_readfirstlane(tid >> 6);
    const int m16  = lane & 15;
    const int quad = lane >> 4;

    // ---- attn GEMM (head s) in two px-halves: A = ctxT[b][s][e][d] (8 MFMAs each)
    const bf16* ctxs = ctxT_bf + (size_t)(b*4 + s) * 1024;
    const bf16* qb   = q_wsT + (size_t)(b*4096 + n0) * 128 + s*32;
    bf16x8 afr[2];
    #pragma unroll
    for (int mt = 0; mt < 2; ++mt)
        afr[mt] = *(const bf16x8*)&ctxs[(mt*16 + m16)*32 + quad*8];

    #pragma unroll 1
    for (int h2 = 0; h2 < 2; ++h2) {
        f32x4 aacc[2][4] = {};
        bf16x8 bfr[4];
        #pragma unroll
        for (int nt = 0; nt < 4; ++nt) {
            int p = (h2*4 + nt)*16 + m16;
            bfr[nt] = *(const bf16x8*)&qb[(size_t)p*128 + quad*8];
        }
        #pragma unroll
        for (int mt = 0; mt < 2; ++mt)
            #pragma unroll
            for (int nt = 0; nt < 4; ++nt)
                aacc[mt][nt] = __builtin_amdgcn_mfma_f32_16x16x32_bf16(afr[mt], bfr[nt], aacc[mt][nt], 0, 0, 0);

        // write attnT[p][ch] swizzled: gp = (ch>>3) ^ (p&15)
        #pragma unroll
        for (int mt = 0; mt < 2; ++mt)
            #pragma unroll
            for (int nt = 0; nt < 4; ++nt) {
                int p   = (h2*4 + nt)*16 + m16;
                int chb = s*32 + mt*16 + quad*4;
                int gp  = (chb >> 3) ^ m16;
                bf16x4 pk = { (bf16)aacc[mt][nt][0], (bf16)aacc[mt][nt][1],
                              (bf16)aacc[mt][nt][2], (bf16)aacc[mt][nt][3] };
                *(bf16x4*)&attnT[p*128 + gp*8 + (quad & 1)*4] = pk;
            }
    }
    __syncthreads();

    // ---- Wout GEMM in four 16-row quarters: rows o = s*64 + qh*16 + m16
    float ls = 0.f, lss = 0.f;
    float* ob = out + ((size_t)b*256 + s*64) * NPIX + n0;
    #pragma unroll 1
    for (int qh = 0; qh < 4; ++qh) {
        f32x4 acc[8] = {};
        const bf16* wb = wout_bf + (size_t)(s*64 + qh*16) * 128;
        for (int kc = 0; kc < 4; ++kc) {
            bf16x8 wfr = *(const bf16x8*)&wb[(size_t)m16*128 + kc*32 + quad*8];
            bf16x8 xfr[8];
            #pragma unroll
            for (int nt = 0; nt < 8; ++nt) {
                int p  = nt*16 + m16;
                int gp = (kc*4 + quad) ^ m16;
                xfr[nt] = *(const bf16x8*)&attnT[p*128 + gp*8];
            }
            #pragma unroll
            for (int nt = 0; nt < 8; ++nt)
                acc[nt] = __builtin_amdgcn_mfma_f32_16x16x32_bf16(wfr, xfr[nt], acc[nt], 0, 0, 0);
        }

        // epilogue for this quarter: bias, coalesced f32 stores, stats
        #pragma unroll
        for (int r = 0; r < 4; ++r) {
            int o = qh*16 + quad*4 + r;
            float bo = bout[s*64 + o];
            #pragma unroll
            for (int nt = 0; nt < 8; ++nt) {
                float v = acc[nt][r] + bo;
                ob[(size_t)o*NPIX + nt*16 + m16] = v;
                ls += v; lss += v*v;
            }
        }
    }

    red[tid] = ls; red[256 + tid] = lss;
    __syncthreads();
    for (int off = 128; off > 0; off >>= 1) {
        if (tid < off) {
            red[tid]       += red[tid + off];
            red[256 + tid] += red[256 + tid + off];
        }
        __syncthreads();
    }
    if (tid == 0) {
        atomicAdd(&gstats[b],      red[0]);
        atomicAdd(&gstats[32 + b], red[256]);
    }
}

// ---------------------------------------------------------------------------
// k5: GroupNorm apply, k4 folded in (each block derives mean/rsqrt from the
// raw sums — 2 scalar loads). Grid-stride, 8192 blocks.
// ---------------------------------------------------------------------------
__global__ __launch_bounds__(256) void k5_norm(
    float* __restrict__ out, const float* __restrict__ gstats,
    const float* __restrict__ gamma, const float* __restrict__ beta)
{
    const float inv_cnt = 1.0f / 1048576.0f;   // 256*4096
    for (size_t gid = (size_t)blockIdx.x * 256 + threadIdx.x;
         gid < 8388608; gid += (size_t)gridDim.x * 256) {
        size_t base = gid * 4;
        int b = (int)(base >> 20);
        int o = (int)((base >> 12) & 255);
        float m   = gstats[b]      * inv_cnt;
        float var = gstats[32 + b] * inv_cnt - m*m;
        float inv = rsqrtf(var + 1e-5f);
        float a = inv * gamma[o];
        float c = beta[o] - m * a;
        float4 v = ((float4*)out)[gid];
        v.x = v.x * a + c; v.y = v.y * a + c;
        v.z = v.z * a + c; v.w = v.w * a + c;
        ((float4*)out)[gid] = v;
    }
}

extern "C" void kernel_launch(void* const* d_in, const int* in_sizes, int n_in,
                              void* d_out, int out_size, void* d_ws, size_t ws_size,
                              hipStream_t stream) {
    const float* x     = (const float*)d_in[0];
    const float* Wqkv  = (const float*)d_in[1];
    const float* bqkv  = (const float*)d_in[2];
    const float* Wout  = (const float*)d_in[3];
    const float* bout  = (const float*)d_in[4];
    const float* gamma = (const float*)d_in[5];
    const float* beta  = (const float*)d_in[6];
    float* out = (float*)d_out;
    float* ws  = (float*)d_ws;

    bf16*  q_wsT   = (bf16*)ws;
    bf16*  wqkv_bf = (bf16*)(ws + 8388608);
    bf16*  wout_bf = (bf16*)(ws + 8437760);
    bf16*  ctxT_bf = (bf16*)(ws + 8454144);
    bf16*  part    = (bf16*)(ws + 16777216);
    float* gstats  = ws + 25165824;

    hipMemsetAsync(gstats, 0, 64 * sizeof(float), stream);
    k0_convert<<<512,  256, 0, stream>>>(Wqkv, Wout, wqkv_bf, wout_bf);
    k1_qkv    <<<2048, 256, 0, stream>>>(x, wqkv_bf, bqkv, q_wsT, part);
    k2_reduce <<<512,  256, 0, stream>>>(part, ctxT_bf);
    k3_out    <<<1024, 256, 0, stream>>>(q_wsT, ctxT_bf, wout_bf, bout, out, gstats);
    k5_norm   <<<8192, 256, 0, stream>>>(out, gstats, gamma, beta);
}

// Round 7
// 366.690 us; speedup vs baseline: 1.1495x; 1.1495x over previous
//
#include <hip/hip_runtime.h>
#include <math.h>

// LinearAttention — all GEMMs bf16 MFMA 16x16x32, fragment loads direct from
// global where layout permits (coalesced 64B lines via 4 quads x 16B).
//
// R1: k1 split into q-pass (32 AGPR) then kv-pass (64 AGPR), (256,4).
// R2: part f32 -> bf16.  k1 = 109 us champion; total 369 champion.
// R3: FAILED (reg-prefetch spilled at 128-reg cap).
// R4: FAILED ((256,3) no payload residency, cost occupancy; k3 halves -9us net).
// R5: FAILED (k3 128-px quarters: 4x attnT LDS re-reads, +50us).
// R6: k3/k5 reverted to R2 shapes (k4 folded into k5). k1 staging rewritten:
//     float4 loads along px (16B/slot, 4x staging bytes-in-flight at equal
//     compiler window) + in-thread 4x4 transpose -> same swizzled xT layout.
//     (R6 bench was an infra failure; resubmitted unchanged.)
//
// ws layout (float units):
//   q_wsT   @ 0         : bf16[32*4096*128]  [b][px][ch] softmaxed*SCALE q   (8388608 f)
//   wqkv_bf @ 8388608   : bf16[384*256]      row-major                      (49152 f)
//   wout_bf @ 8437760   : bf16[256*128]      row-major                      (16384 f)
//   ctxT_bf @ 8454144   : bf16[32*4*32*32]   [b][h][e][d] (transposed)      (65536 f)
//   part    @ 16777216  : bf16[2048][4096]   per-block context partials     (4194304 f)
//   gstats  @ 25165824  : f32 [128]

#define NPIX 4096
#define SCALE 0.17677669529663687f

typedef __bf16 bf16;
typedef __bf16 bf16x4 __attribute__((ext_vector_type(4)));
typedef __bf16 bf16x8 __attribute__((ext_vector_type(8)));
typedef float  f32x4  __attribute__((ext_vector_type(4)));

// ---------------------------------------------------------------------------
__global__ __launch_bounds__(256) void k0_convert(
    const float* __restrict__ Wqkv, const float* __restrict__ Wout,
    bf16* __restrict__ wqkv_bf, bf16* __restrict__ wout_bf)
{
    int i = blockIdx.x * 256 + threadIdx.x;   // < 131072
    if (i < 98304) wqkv_bf[i] = (bf16)Wqkv[i];
    else           wout_bf[i - 98304] = (bf16)Wout[i - 98304];
}

// ---------------------------------------------------------------------------
// k1: block = (batch b, 64-px tile). 4 waves, wave s = head s.
// qkv[384,64] = Wqkv x x. A-frags direct from global bf16 Wqkv (L2-hot).
// B-frags from LDS xT (transposed, XOR-swizzled). Barrier-free K-loop.
// Staging (R6): 16 x float4 loads (4 px x 1 ch each, 16B/slot); the 4x4
// (px x ch) block sits in one thread's regs, so the transposed bf16x4-along-ch
// pack is free register selection. Same xT layout/swizzle as before.
// LDS: xT 16384 bf16 (32 KB); overlay phase2: k/v [4][32][72]*2 = 36864 B.
// ---------------------------------------------------------------------------
__global__ __launch_bounds__(256, 4) void k1_qkv(
    const float* __restrict__ x, const bf16* __restrict__ wqkv_bf,
    const float* __restrict__ bqkv, bf16* __restrict__ q_wsT,
    bf16* __restrict__ part)
{
    __shared__ __align__(16) bf16 sm[18432];   // 36864 B
    bf16* xT = sm;   // 16384 bf16 [px][256ch], group(8) swizzle gp = g ^ (px&7)

    const int blk  = blockIdx.x;
    const int b    = blk >> 6;
    const int n0   = (blk & 63) << 6;
    const int tid  = threadIdx.x;
    const int lane = tid & 63;
    const int s    = __builtin_amdgcn_readfirstlane(tid >> 6);
    const int m16  = lane & 15;
    const int quad = lane >> 4;

    // stage xT: float4 (4 px) x 4 ch rows per iter; 16 dwordx4 loads issued
    // before any convert/write (sched_barrier pins the split).
    const float* xb = x + (size_t)b * (256 * NPIX) + n0;
    {
        const int p4  = tid & 15;    // px quad index (px = 4*p4 + j)
        const int cqb = tid >> 4;    // ch-quad base (0..15)
        f32x4 vv[4][4];
        #pragma unroll
        for (int i = 0; i < 4; ++i) {
            int chq = cqb + 16*i;
            #pragma unroll
            for (int cc = 0; cc < 4; ++cc)
                vv[i][cc] = *(const f32x4*)(xb + (size_t)(chq*4 + cc) * NPIX + p4*4);
        }
        __builtin_amdgcn_sched_barrier(0);
        #pragma unroll
        for (int i = 0; i < 4; ++i) {
            int chq = cqb + 16*i;
            int g   = chq >> 1;
            int o   = (chq & 1) * 4;
            #pragma unroll
            for (int j = 0; j < 4; ++j) {
                int px = p4*4 + j;
                int gp = g ^ (px & 7);
                bf16x4 pk = { (bf16)vv[i][0][j], (bf16)vv[i][1][j],
                              (bf16)vv[i][2][j], (bf16)vv[i][3][j] };
                *(bf16x4*)&xT[px*256 + gp*8 + o] = pk;
            }
        }
    }
    __syncthreads();

    // ---- pass 1: q GEMM (rows s*32 .. s*32+31), softmax over d, store q_wsT
    {
        f32x4 qacc[2][4] = {};
        for (int kc = 0; kc < 8; ++kc) {
            bf16x8 bfr[4];
            #pragma unroll
            for (int nt = 0; nt < 4; ++nt) {
                int px = nt*16 + m16;
                int gp = (kc*4 + quad) ^ (px & 7);
                bfr[nt] = *(const bf16x8*)&xT[px*256 + gp*8];
            }
            #pragma unroll
            for (int mt = 0; mt < 2; ++mt) {
                int row = s*32 + mt*16 + m16;
                bf16x8 afr = *(const bf16x8*)&wqkv_bf[(size_t)row*256 + kc*32 + quad*8];
                #pragma unroll
                for (int nt = 0; nt < 4; ++nt)
                    qacc[mt][nt] = __builtin_amdgcn_mfma_f32_16x16x32_bf16(afr, bfr[nt], qacc[mt][nt], 0, 0, 0);
            }
        }
        float bq[8];
        #pragma unroll
        for (int j = 0; j < 8; ++j)
            bq[j] = bqkv[s*32 + (j >> 2)*16 + quad*4 + (j & 3)];

        #pragma unroll
        for (int nt = 0; nt < 4; ++nt) {
            float v[8]; float mx = -1e30f;
            #pragma unroll
            for (int j = 0; j < 8; ++j) { v[j] = qacc[j>>2][nt][j&3] + bq[j]; mx = fmaxf(mx, v[j]); }
            mx = fmaxf(mx, __shfl_xor(mx, 16));
            mx = fmaxf(mx, __shfl_xor(mx, 32));
            float sum = 0.f;
            #pragma unroll
            for (int j = 0; j < 8; ++j) { v[j] = __expf(v[j] - mx); sum += v[j]; }
            sum += __shfl_xor(sum, 16);
            sum += __shfl_xor(sum, 32);
            float rs = SCALE / sum;
            size_t rowb = (size_t)(b*4096 + n0 + nt*16 + m16) * 128;
            #pragma unroll
            for (int mt = 0; mt < 2; ++mt) {
                bf16x4 pk = { (bf16)(v[mt*4+0]*rs), (bf16)(v[mt*4+1]*rs),
                              (bf16)(v[mt*4+2]*rs), (bf16)(v[mt*4+3]*rs) };
                *(bf16x4*)&q_wsT[rowb + s*32 + mt*16 + quad*4] = pk;
            }
        }
    }

    // ---- pass 2: k,v GEMM (rows 128+s*32.. and 256+s*32..)
    f32x4 acc[4][4] = {};   // m-tiles: k0,k1,v0,v1 ; 4 n-tiles
    for (int kc = 0; kc < 8; ++kc) {
        bf16x8 bfr[4];
        #pragma unroll
        for (int nt = 0; nt < 4; ++nt) {
            int px = nt*16 + m16;
            int gp = (kc*4 + quad) ^ (px & 7);
            bfr[nt] = *(const bf16x8*)&xT[px*256 + gp*8];
        }
        #pragma unroll
        for (int mt = 0; mt < 4; ++mt) {
            int row = 128 + (mt >> 1)*128 + s*32 + (mt & 1)*16 + m16;
            bf16x8 afr = *(const bf16x8*)&wqkv_bf[(size_t)row*256 + kc*32 + quad*8];
            #pragma unroll
            for (int nt = 0; nt < 4; ++nt)
                acc[mt][nt] = __builtin_amdgcn_mfma_f32_16x16x32_bf16(afr, bfr[nt], acc[mt][nt], 0, 0, 0);
        }
    }

    float bk[8], bv[8];
    #pragma unroll
    for (int j = 0; j < 8; ++j) {
        int rr = (j >> 2)*16 + quad*4 + (j & 3);
        bk[j] = bqkv[128 + s*32 + rr];
        bv[j] = bqkv[256 + s*32 + rr];
    }

    // k softmax + v bias -> LDS overlay (xT dead; barrier for WAR)
    __syncthreads();
    bf16* kl = sm + s*2304;          // [32][72]
    bf16* vl = sm + 9216 + s*2304;   // [32][72]
    #pragma unroll
    for (int nt = 0; nt < 4; ++nt) {
        float v[8]; float mx = -1e30f;
        #pragma unroll
        for (int j = 0; j < 8; ++j) { v[j] = acc[j>>2][nt][j&3] + bk[j]; mx = fmaxf(mx, v[j]); }
        mx = fmaxf(mx, __shfl_xor(mx, 16));
        mx = fmaxf(mx, __shfl_xor(mx, 32));
        float sum = 0.f;
        #pragma unroll
        for (int j = 0; j < 8; ++j) { v[j] = __expf(v[j] - mx); sum += v[j]; }
        sum += __shfl_xor(sum, 16);
        sum += __shfl_xor(sum, 32);
        float rs = 1.f / sum;
        #pragma unroll
        for (int j = 0; j < 8; ++j) {
            int d  = (j>>2)*16 + quad*4 + (j&3);
            int px = nt*16 + m16;
            kl[d*72 + px] = (bf16)(v[j] * rs);
            vl[d*72 + px] = (bf16)(acc[2 + (j>>2)][nt][j&3] + bv[j]);
        }
    }
    __syncthreads();

    // context partial: ctx[d][e] = sum_p k[d][p]*v[e][p]
    f32x4 cacc[2][2] = {};
    #pragma unroll
    for (int ks = 0; ks < 2; ++ks) {
        bf16x8 ak[2], bvv[2];
        #pragma unroll
        for (int mt = 0; mt < 2; ++mt)
            ak[mt] = *(const bf16x8*)&kl[(mt*16 + m16)*72 + ks*32 + quad*8];
        #pragma unroll
        for (int nt = 0; nt < 2; ++nt)
            bvv[nt] = *(const bf16x8*)&vl[(nt*16 + m16)*72 + ks*32 + quad*8];
        #pragma unroll
        for (int mt = 0; mt < 2; ++mt)
            #pragma unroll
            for (int nt = 0; nt < 2; ++nt)
                cacc[mt][nt] = __builtin_amdgcn_mfma_f32_16x16x32_bf16(ak[mt], bvv[nt], cacc[mt][nt], 0, 0, 0);
    }
    bf16* pdst = part + (size_t)blk * 4096 + s*1024;
    #pragma unroll
    for (int mt = 0; mt < 2; ++mt)
        #pragma unroll
        for (int nt = 0; nt < 2; ++nt)
            #pragma unroll
            for (int r = 0; r < 4; ++r)
                pdst[(mt*16 + quad*4 + r)*32 + nt*16 + m16] = (bf16)cacc[mt][nt][r];
}

// ---------------------------------------------------------------------------
__global__ __launch_bounds__(256) void k2_reduce(
    const bf16* __restrict__ part, bf16* __restrict__ ctxT_bf)
{
    int i = blockIdx.x * 256 + threadIdx.x;   // < 131072
    int b = i >> 12, r = i & 4095;
    const bf16* p = part + (size_t)b * 64 * 4096 + r;
    float sum = 0.f;
    #pragma unroll 8
    for (int j = 0; j < 64; ++j) sum += (float)p[(size_t)j * 4096];
    int h = r >> 10, d = (r >> 5) & 31, e = r & 31;
    ctxT_bf[(size_t)((b*4 + h)*32 + e)*32 + d] = (bf16)sum;   // transposed
}

// ---------------------------------------------------------------------------
// k3: block = (b, 64-px tile). Wave s: attn for head s, then out rows s*64..+63.
// (R2-exact body — the R4/R5 splits regressed; single-pass 4x4 acc is best.)
// attn[e][p] = ctxT x qT  (frags direct from global, 8 MFMAs)
// out = Wout x attn       (A direct from global bf16 Wout; B from LDS attnT)
// LDS: attnT [64][128] bf16 XOR-swizzled (16 KB) + red[512] f32.
// ---------------------------------------------------------------------------
__global__ __launch_bounds__(256) void k3_out(
    const bf16* __restrict__ q_wsT, const bf16* __restrict__ ctxT_bf,
    const bf16* __restrict__ wout_bf, const float* __restrict__ bout,
    float* __restrict__ out, float* __restrict__ gstats)
{
    __shared__ __align__(16) bf16 attnT[8192];
    __shared__ float red[512];
    const int blk  = blockIdx.x;
    const int b    = blk >> 6;
    const int n0   = (blk & 63) << 6;
    const int tid  = threadIdx.x;
    const int lane = tid & 63;
    const int s    = __builtin_amdgcn_readfirstlane(tid >> 6);
    const int m16  = lane & 15;
    const int quad = lane >> 4;

    // ---- attn GEMM (head s): A = ctxT[b][s][e][d], B^T = q_wsT[b][px][s*32+d]
    f32x4 aacc[2][4] = {};
    {
        bf16x8 afr[2], bfr[4];
        const bf16* ctxs = ctxT_bf + (size_t)(b*4 + s) * 1024;
        #pragma unroll
        for (int mt = 0; mt < 2; ++mt)
            afr[mt] = *(const bf16x8*)&ctxs[(mt*16 + m16)*32 + quad*8];
        const bf16* qb = q_wsT + (size_t)(b*4096 + n0) * 128 + s*32;
        #pragma unroll
        for (int nt = 0; nt < 4; ++nt)
            bfr[nt] = *(const bf16x8*)&qb[(size_t)(nt*16 + m16)*128 + quad*8];
        #pragma unroll
        for (int mt = 0; mt < 2; ++mt)
            #pragma unroll
            for (int nt = 0; nt < 4; ++nt)
                aacc[mt][nt] = __builtin_amdgcn_mfma_f32_16x16x32_bf16(afr[mt], bfr[nt], aacc[mt][nt], 0, 0, 0);
    }

    // write attnT[p][ch] swizzled: gp = (ch>>3) ^ (p&15)
    #pragma unroll
    for (int mt = 0; mt < 2; ++mt)
        #pragma unroll
        for (int nt = 0; nt < 4; ++nt) {
            int p   = nt*16 + m16;
            int chb = s*32 + mt*16 + quad*4;
            int gp  = (chb >> 3) ^ m16;
            bf16x4 pk = { (bf16)aacc[mt][nt][0], (bf16)aacc[mt][nt][1],
                          (bf16)aacc[mt][nt][2], (bf16)aacc[mt][nt][3] };
            *(bf16x4*)&attnT[p*128 + gp*8 + (quad & 1)*4] = pk;
        }
    __syncthreads();

    // ---- Wout GEMM: rows o = s*64 + mt*16 + m16, K = 128 (4 chunks)
    f32x4 acc[4][4] = {};
    const bf16* wb = wout_bf + (size_t)s * 64 * 128;
    for (int kc = 0; kc < 4; ++kc) {
        bf16x8 wfr[4], xfr[4];
        #pragma unroll
        for (int mt = 0; mt < 4; ++mt)
            wfr[mt] = *(const bf16x8*)&wb[(size_t)(mt*16 + m16)*128 + kc*32 + quad*8];
        #pragma unroll
        for (int nt = 0; nt < 4; ++nt) {
            int p  = nt*16 + m16;
            int gp = (kc*4 + quad) ^ m16;
            xfr[nt] = *(const bf16x8*)&attnT[p*128 + gp*8];
        }
        #pragma unroll
        for (int mt = 0; mt < 4; ++mt)
            #pragma unroll
            for (int nt = 0; nt < 4; ++nt)
                acc[mt][nt] = __builtin_amdgcn_mfma_f32_16x16x32_bf16(wfr[mt], xfr[nt], acc[mt][nt], 0, 0, 0);
    }

    // epilogue: bias, coalesced f32 stores, per-lane stats
    float ls = 0.f, lss = 0.f;
    float* ob = out + ((size_t)b*256 + s*64) * NPIX + n0;
    #pragma unroll
    for (int mt = 0; mt < 4; ++mt) {
        #pragma unroll
        for (int r = 0; r < 4; ++r) {
            int o = mt*16 + quad*4 + r;
            float bo = bout[s*64 + o];
            #pragma unroll
            for (int nt = 0; nt < 4; ++nt) {
                float v = acc[mt][nt][r] + bo;
                ob[(size_t)o*NPIX + nt*16 + m16] = v;
                ls += v; lss += v*v;
            }
        }
    }

    red[tid] = ls; red[256 + tid] = lss;
    __syncthreads();
    for (int off = 128; off > 0; off >>= 1) {
        if (tid < off) {
            red[tid]       += red[tid + off];
            red[256 + tid] += red[256 + tid + off];
        }
        __syncthreads();
    }
    if (tid == 0) {
        atomicAdd(&gstats[b],      red[0]);
        atomicAdd(&gstats[32 + b], red[256]);
    }
}

// ---------------------------------------------------------------------------
// k5: GroupNorm apply (k4 folded in: mean/rsqrt derived from raw sums — two
// wave-uniform scalar loads). Same 32768-block one-shot shape as R2.
// ---------------------------------------------------------------------------
__global__ __launch_bounds__(256) void k5_norm(
    float* __restrict__ out, const float* __restrict__ gstats,
    const float* __restrict__ gamma, const float* __restrict__ beta)
{
    const float inv_cnt = 1.0f / 1048576.0f;   // 256*4096
    size_t gid  = (size_t)blockIdx.x * 256 + threadIdx.x;
    size_t base = gid * 4;
    int b = (int)(base >> 20);
    int o = (int)((base >> 12) & 255);
    float m   = gstats[b]      * inv_cnt;
    float var = gstats[32 + b] * inv_cnt - m*m;
    float inv = rsqrtf(var + 1e-5f);
    float a = inv * gamma[o];
    float c = beta[o] - m * a;
    float4 v = ((float4*)out)[gid];
    v.x = v.x * a + c; v.y = v.y * a + c;
    v.z = v.z * a + c; v.w = v.w * a + c;
    ((float4*)out)[gid] = v;
}

extern "C" void kernel_launch(void* const* d_in, const int* in_sizes, int n_in,
                              void* d_out, int out_size, void* d_ws, size_t ws_size,
                              hipStream_t stream) {
    const float* x     = (const float*)d_in[0];
    const float* Wqkv  = (const float*)d_in[1];
    const float* bqkv  = (const float*)d_in[2];
    const float* Wout  = (const float*)d_in[3];
    const float* bout  = (const float*)d_in[4];
    const float* gamma = (const float*)d_in[5];
    const float* beta  = (const float*)d_in[6];
    float* out = (float*)d_out;
    float* ws  = (float*)d_ws;

    bf16*  q_wsT   = (bf16*)ws;
    bf16*  wqkv_bf = (bf16*)(ws + 8388608);
    bf16*  wout_bf = (bf16*)(ws + 8437760);
    bf16*  ctxT_bf = (bf16*)(ws + 8454144);
    bf16*  part    = (bf16*)(ws + 16777216);
    float* gstats  = ws + 25165824;

    hipMemsetAsync(gstats, 0, 64 * sizeof(float), stream);
    k0_convert<<<512,  256, 0, stream>>>(Wqkv, Wout, wqkv_bf, wout_bf);
    k1_qkv    <<<2048, 256, 0, stream>>>(x, wqkv_bf, bqkv, q_wsT, part);
    k2_reduce <<<512,  256, 0, stream>>>(part, ctxT_bf);
    k3_out    <<<2048, 256, 0, stream>>>(q_wsT, ctxT_bf, wout_bf, bout, out, gstats);
    k5_norm   <<<32768,256, 0, stream>>>(out, gstats, gamma, beta);
}